// Round 15
// baseline (542.464 us; speedup 1.0000x reference)
//
#include <hip/hip_runtime.h>

#define NODE_DIM 128
#define NUM_IRREPS 224
#define SPH_DIM 480
#define HIDDEN 576   // NODE_DIM + 2*NUM_IRREPS
#define NUM_BASIS 20
#define N_NODES 10000
#define N_EDGES 160000
#define NPB 4        // nodes per block in fused MLP
#define EB 16        // edges per chunk
#define NT 36        // N-tiles (576/16)
#define IRP 233      // pair row stride in words (odd)
#define SCP 138      // scal row stride in shorts (odd word count)
#define PREP_BLOCKS 625                       // 625*256 = 160000 (histogram)
#define MLP_BLOCKS ((N_NODES + NPB - 1) / NPB)

typedef __attribute__((ext_vector_type(8))) short short8v;   // 8 bf16
typedef __attribute__((ext_vector_type(4))) float f32x4;

__device__ __forceinline__ unsigned short f2bf(float f) {
    unsigned int u = __builtin_bit_cast(unsigned int, f);
    u = (u + 0x7fff + ((u >> 16) & 1)) >> 16;   // RNE
    return (unsigned short)u;
}
__device__ __forceinline__ float bf2f(unsigned short h) {
    unsigned int u = ((unsigned int)h) << 16;
    return __builtin_bit_cast(float, u);
}
__device__ __forceinline__ int gate_of(int d) {
    return (d < 128) ? d : (d < 320) ? (128 + (d - 128) / 3) : (192 + (d - 320) / 5);
}

// ---------------- fused prep (histogram + bfrag) + node MLP ----------------
__global__ __launch_bounds__(256) void prep_mlp_kernel(
    const float* __restrict__ xs,
    const int* __restrict__ eidx, int* __restrict__ counts,
    const float* __restrict__ Wr, unsigned short* __restrict__ bfrag,
    const float* __restrict__ W1, const float* __restrict__ b1,
    const float* __restrict__ W2, const float* __restrict__ b2,
    unsigned short* __restrict__ so_bf)
{
    const int t = threadIdx.x;
    if (blockIdx.x < PREP_BLOCKS) {
        const int gt = blockIdx.x * 256 + t;
        if (gt < N_EDGES) atomicAdd(&counts[eidx[gt]], 1);
        if (blockIdx.x == PREP_BLOCKS - 1) {
            for (int idx = t; idx < NT * 64; idx += 256) {
                const int nt = idx >> 6, l = idx & 63;
                const int col = nt * 16 + (l & 15);
                const int kb = (l >> 4) * 8;
                #pragma unroll
                for (int j = 0; j < 8; ++j) {
                    const int k = kb + j;
                    bfrag[(size_t)idx * 8 + j] = (k < NUM_BASIS) ? f2bf(Wr[k * HIDDEN + col]) : (unsigned short)0;
                }
            }
        }
        return;
    }
    // ---- node MLP: 256 threads, 4 nodes/block ----
    __shared__ float xsm[NPB][NODE_DIM];
    __shared__ float hsm[NPB][NODE_DIM];
    const int n0 = (blockIdx.x - PREP_BLOCKS) * NPB;
    const int half = t >> 7;
    const int tc = t & 127;

    #pragma unroll
    for (int i = 0; i < 2; ++i) {
        const int nn = 2 * half + i;
        const int node = n0 + nn;
        xsm[nn][tc] = (node < N_NODES) ? xs[(size_t)node * NODE_DIM + tc] : 0.f;
    }
    __syncthreads();

    float acc[2] = {b1[tc], b1[tc]};
    for (int k = 0; k < NODE_DIM; ++k) {
        const float w = W1[k * NODE_DIM + tc];
        #pragma unroll
        for (int i = 0; i < 2; ++i) acc[i] = fmaf(xsm[2 * half + i][k], w, acc[i]);
    }
    #pragma unroll
    for (int i = 0; i < 2; ++i) {
        const float v = acc[i];
        hsm[2 * half + i][tc] = v / (1.f + __expf(-v));
    }
    __syncthreads();

    for (int j = t; j < HIDDEN; j += 256) {
        float a2[NPB];
        #pragma unroll
        for (int n = 0; n < NPB; ++n) a2[n] = b2[j];
        for (int k = 0; k < NODE_DIM; ++k) {
            const float w = W2[k * HIDDEN + j];
            #pragma unroll
            for (int n = 0; n < NPB; ++n) a2[n] = fmaf(hsm[n][k], w, a2[n]);
        }
        #pragma unroll
        for (int n = 0; n < NPB; ++n) {
            const int node = n0 + n;
            if (node < N_NODES) so_bf[(size_t)node * HIDDEN + j] = f2bf(a2[n]);
        }
    }
}

// ---------------- CSR scan / scatter ----------------
__global__ __launch_bounds__(1024) void scan_kernel(const int* __restrict__ counts,
                                                    int* __restrict__ offsets,
                                                    int* __restrict__ cursor) {
    __shared__ int wsum[16];
    const int tid = threadIdx.x;
    int vals[10];
    int run = 0;
    #pragma unroll
    for (int i = 0; i < 10; ++i) {
        int idx = tid * 10 + i;
        int c = (idx < N_NODES) ? counts[idx] : 0;
        vals[i] = run;
        run += c;
    }
    const int lane = tid & 63, w = tid >> 6;
    int inc = run;
    #pragma unroll
    for (int off = 1; off < 64; off <<= 1) {
        int v = __shfl_up(inc, off);
        if (lane >= off) inc += v;
    }
    if (lane == 63) wsum[w] = inc;
    __syncthreads();
    if (w == 0) {
        int v = (lane < 16) ? wsum[lane] : 0;
        #pragma unroll
        for (int off = 1; off < 16; off <<= 1) {
            int u = __shfl_up(v, off);
            if (lane >= off) v += u;
        }
        if (lane < 16) wsum[lane] = v;
    }
    __syncthreads();
    const int wbase = (w > 0) ? wsum[w - 1] : 0;
    const int base = wbase + inc - run;   // exclusive prefix
    #pragma unroll
    for (int i = 0; i < 10; ++i) {
        int idx = tid * 10 + i;
        if (idx < N_NODES) {
            int v = base + vals[i];
            offsets[idx] = v;
            cursor[idx] = v;
        }
    }
    if (tid == 1023) offsets[N_NODES] = wbase + inc;
}

__global__ __launch_bounds__(256) void scatter_kernel(const int* __restrict__ eidx,
                                                      int* __restrict__ cursor,
                                                      int* __restrict__ edge_order) {
    int i = blockIdx.x * blockDim.x + threadIdx.x;
    if (i < N_EDGES) {
        int s = eidx[i];
        int pos = atomicAdd(&cursor[s], 1);
        edge_order[pos] = i;
    }
}

// ---------------- node MFMA kernel: one block per node, no atomics ----------------
// Walks the node's CSR segment in 16-edge chunks:
//   Phase A: rbf(16x32 bf16, 2xfloat4 loads) @ Wr-frags on matrix cores;
//            epilogue fo=(acc+br)*fcut*so[dst] -> paired bf16 LDS.
//   Phase B: thread t<240 owns d=2t,2t+1 (float2 xsp/rsh); t<128 scalar col t.
// Epilogue: single coalesced store out = x + acc. Zero-degree nodes write x.
__global__ __launch_bounds__(256, 4) void node_mfma(
    const float* __restrict__ xs, const float* __restrict__ xsp,
    const float* __restrict__ rbf, const float* __restrict__ fcut,
    const float* __restrict__ rsh, const int* __restrict__ eidx,
    const unsigned short* __restrict__ bfrag, const float* __restrict__ br,
    const unsigned short* __restrict__ so_bf,
    const int* __restrict__ offsets, const int* __restrict__ edge_order,
    float* __restrict__ out_scalar, float* __restrict__ out_sph)
{
    __shared__ unsigned int   pair_s[EB][IRP];    // 14.9 KB
    __shared__ unsigned short scal_s[EB][SCP];    // 4.4 KB
    __shared__ int   e_s[EB];
    __shared__ int   dst_s[EB];
    __shared__ float fc_s[EB];

    const int t = threadIdx.x;
    const int n = blockIdx.x;
    const int lane = t & 63, w = t >> 6;
    const int beg = offsets[n], end_ = offsets[n + 1];

    const bool sphOn = (t < 240);
    const int d0 = 2 * t;
    const int g0 = sphOn ? gate_of(d0) : 0;
    const int g1 = sphOn ? gate_of(d0 + 1) : 0;

    float accS = 0.f, accD0 = 0.f, accD1 = 0.f;

    for (int chunk = beg; chunk < end_; chunk += EB) {
        const int cnt = min(EB, end_ - chunk);
        if (t < EB) {
            if (t < cnt) {
                const int e = edge_order[chunk + t];
                e_s[t]   = e;
                dst_s[t] = eidx[N_EDGES + e];
                fc_s[t]  = fcut[e];
            } else {
                e_s[t] = 0; dst_s[t] = 0; fc_s[t] = 0.f;
            }
        }
        __syncthreads();

        // ---- A-fragment: 2x float4 from rbf row (lane: edge row l&15, k=(l>>4)*8+j) ----
        const int m_row = lane & 15;
        const int kb = (lane >> 4) * 8;
        short8v a0;
        {
            const int er = edge_order[chunk + min(m_row, cnt - 1)];
            const float* rrow = rbf + (size_t)er * NUM_BASIS;
            float q[8];
            if (kb < 16) {          // kb = 0 or 8: full 8 floats
                const float4 v0 = *(const float4*)(rrow + kb);
                const float4 v1 = *(const float4*)(rrow + kb + 4);
                q[0]=v0.x; q[1]=v0.y; q[2]=v0.z; q[3]=v0.w;
                q[4]=v1.x; q[5]=v1.y; q[6]=v1.z; q[7]=v1.w;
            } else if (kb == 16) {  // k=16..19 valid
                const float4 v0 = *(const float4*)(rrow + 16);
                q[0]=v0.x; q[1]=v0.y; q[2]=v0.z; q[3]=v0.w;
                q[4]=0.f; q[5]=0.f; q[6]=0.f; q[7]=0.f;
            } else {
                #pragma unroll
                for (int j = 0; j < 8; ++j) q[j] = 0.f;
            }
            #pragma unroll
            for (int j = 0; j < 8; ++j) a0[j] = (short)f2bf(q[j]);
        }

        // ---- phase A: 9 N-tiles per wave ----
        {
            const int rbase = (lane >> 4) * 4;
            int dA[4]; float fA[4];
            #pragma unroll
            for (int r = 0; r < 4; ++r) { dA[r] = dst_s[rbase + r]; fA[r] = fc_s[rbase + r]; }
            #pragma unroll
            for (int i = 0; i < NT / 4; ++i) {
                const int nt = w * (NT / 4) + i;
                const short8v bf = *(const short8v*)(bfrag + (size_t)(nt * 64 + lane) * 8);
                f32x4 c0 = {0.f, 0.f, 0.f, 0.f};
                c0 = __builtin_amdgcn_mfma_f32_16x16x32_bf16(a0, bf, c0, 0, 0, 0);
                const int col = nt * 16 + (lane & 15);
                const float brc = br[col];
                #pragma unroll
                for (int r = 0; r < 4; ++r) {
                    const int row = rbase + r;
                    const float sov = bf2f(so_bf[(size_t)dA[r] * HIDDEN + col]);
                    const float v = (c0[r] + brc) * fA[r] * sov;
                    const unsigned short hv = f2bf(v);
                    if (col < NUM_IRREPS) {
                        ((unsigned short*)&pair_s[row][col])[0] = hv;              // state (lo)
                    } else if (col < 2 * NUM_IRREPS) {
                        ((unsigned short*)&pair_s[row][col - NUM_IRREPS])[1] = hv; // edge (hi)
                    } else {
                        scal_s[row][col - 2 * NUM_IRREPS] = hv;
                    }
                }
            }
        }
        __syncthreads();

        // ---- phase B: accumulate this chunk ----
        for (int le = 0; le < cnt; ++le) {
            if (sphOn) {
                const float2 xv = *(const float2*)(xsp + (size_t)dst_s[le] * SPH_DIM + d0);
                const float2 rv = *(const float2*)(rsh + (size_t)e_s[le]  * SPH_DIM + d0);
                const unsigned int p0 = pair_s[le][g0];
                const unsigned int p1 = pair_s[le][g1];
                accD0 = fmaf(xv.x, bf2f((unsigned short)(p0 & 0xffffu)),
                        fmaf(rv.x, bf2f((unsigned short)(p0 >> 16)), accD0));
                accD1 = fmaf(xv.y, bf2f((unsigned short)(p1 & 0xffffu)),
                        fmaf(rv.y, bf2f((unsigned short)(p1 >> 16)), accD1));
            }
            if (t < 128) accS += bf2f(scal_s[le][t]);
        }
        __syncthreads();   // protect LDS reuse by next chunk
    }

    // ---- epilogue: single coalesced store out = x + acc ----
    if (t < 128)
        out_scalar[(size_t)n * NODE_DIM + t] = xs[(size_t)n * NODE_DIM + t] + accS;
    if (sphOn) {
        const float2 xv = *(const float2*)(xsp + (size_t)n * SPH_DIM + d0);
        float2 o; o.x = xv.x + accD0; o.y = xv.y + accD1;
        *(float2*)(out_sph + (size_t)n * SPH_DIM + d0) = o;
    }
}

extern "C" void kernel_launch(void* const* d_in, const int* in_sizes, int n_in,
                              void* d_out, int out_size, void* d_ws, size_t ws_size,
                              hipStream_t stream) {
    const float* x_scalar    = (const float*)d_in[0];
    const float* x_spherical = (const float*)d_in[1];
    const float* rbf         = (const float*)d_in[2];
    const float* fcut        = (const float*)d_in[3];
    const float* rsh         = (const float*)d_in[4];
    const int*   eidx        = (const int*)d_in[5];
    const float* W1          = (const float*)d_in[6];
    const float* b1          = (const float*)d_in[7];
    const float* W2          = (const float*)d_in[8];
    const float* b2          = (const float*)d_in[9];
    const float* Wr          = (const float*)d_in[10];
    const float* br          = (const float*)d_in[11];

    float* out        = (float*)d_out;
    float* out_scalar = out;                                   // (N_NODES, 128)
    float* out_sph    = out + (size_t)N_NODES * NODE_DIM;      // (N_NODES, 480)

    // workspace layout
    unsigned short* so_bf = (unsigned short*)d_ws;             // 10000*576 bf16
    int*   counts     = (int*)(so_bf + (size_t)N_NODES * HIDDEN);
    int*   offsets    = counts + N_NODES;                      // 10001
    int*   cursor     = offsets + N_NODES + 1;                 // 10000
    int*   edge_order = cursor + N_NODES;                      // 160000
    unsigned short* bfrag = (unsigned short*)((((uintptr_t)(edge_order + N_EDGES)) + 15) & ~(uintptr_t)15);

    hipMemsetAsync(counts, 0, N_NODES * sizeof(int), stream);
    prep_mlp_kernel<<<PREP_BLOCKS + MLP_BLOCKS, 256, 0, stream>>>(
        x_scalar, eidx, counts, Wr, bfrag, W1, b1, W2, b2, so_bf);
    scan_kernel<<<1, 1024, 0, stream>>>(counts, offsets, cursor);
    scatter_kernel<<<(N_EDGES + 255) / 256, 256, 0, stream>>>(eidx, cursor, edge_order);
    node_mfma<<<N_NODES, 256, 0, stream>>>(x_scalar, x_spherical, rbf, fcut, rsh, eidx,
                                           bfrag, br, so_bf, offsets, edge_order,
                                           out_scalar, out_sph);
}

// Round 16
// 336.224 us; speedup vs baseline: 1.6134x; 1.6134x over previous
//
#include <hip/hip_runtime.h>

#define NODE_DIM 128
#define NUM_IRREPS 224
#define SPH_DIM 480
#define HIDDEN 576   // NODE_DIM + 2*NUM_IRREPS
#define NUM_BASIS 20
#define N_NODES 10000
#define N_EDGES 160000
#define NPB 4        // nodes per block in fused MLP
#define EB 16        // edges per window
#define NT 36        // N-tiles (576/16)
#define IRP 233      // pair row stride in words (odd)
#define SCP 138      // scal row stride in shorts
#define MAXW 19400   // > max possible windows (10000 + 160000/16 - eps)
#define PREP_BLOCKS 2048
#define MLP_BLOCKS ((N_NODES + NPB - 1) / NPB)

typedef __attribute__((ext_vector_type(8))) short short8v;   // 8 bf16
typedef __attribute__((ext_vector_type(4))) float f32x4;

__device__ __forceinline__ unsigned short f2bf(float f) {
    unsigned int u = __builtin_bit_cast(unsigned int, f);
    u = (u + 0x7fff + ((u >> 16) & 1)) >> 16;   // RNE
    return (unsigned short)u;
}
__device__ __forceinline__ float bf2f(unsigned short h) {
    unsigned int u = ((unsigned int)h) << 16;
    return __builtin_bit_cast(float, u);
}
__device__ __forceinline__ int gate_of(int d) {
    return (d < 128) ? d : (d < 320) ? (128 + (d - 128) / 3) : (192 + (d - 320) / 5);
}

// ---------------- fused prep (out=x copy + histogram + bfrag) + node MLP ----------------
__global__ __launch_bounds__(256) void prep_mlp_kernel(
    const float* __restrict__ xs, const float* __restrict__ xsp,
    float* __restrict__ out,
    const int* __restrict__ eidx, int* __restrict__ counts,
    const float* __restrict__ Wr, unsigned short* __restrict__ bfrag,
    const float* __restrict__ W1, const float* __restrict__ b1,
    const float* __restrict__ W2, const float* __restrict__ b2,
    unsigned short* __restrict__ so_bf)
{
    const int t = threadIdx.x;
    if (blockIdx.x < PREP_BLOCKS) {
        const int stride = PREP_BLOCKS * 256;
        const int gt = blockIdx.x * 256 + t;
        for (int i = gt; i < N_NODES * NODE_DIM; i += stride) out[i] = xs[i];
        float* o2 = out + (size_t)N_NODES * NODE_DIM;
        for (int i = gt; i < N_NODES * SPH_DIM; i += stride) o2[i] = xsp[i];
        if (gt < N_EDGES) atomicAdd(&counts[eidx[gt]], 1);
        if (blockIdx.x == PREP_BLOCKS - 1) {
            for (int idx = t; idx < NT * 64; idx += 256) {
                const int nt = idx >> 6, l = idx & 63;
                const int col = nt * 16 + (l & 15);
                const int kb = (l >> 4) * 8;
                #pragma unroll
                for (int j = 0; j < 8; ++j) {
                    const int k = kb + j;
                    bfrag[(size_t)idx * 8 + j] = (k < NUM_BASIS) ? f2bf(Wr[k * HIDDEN + col]) : (unsigned short)0;
                }
            }
        }
        return;
    }
    // ---- node MLP: 256 threads, 4 nodes/block ----
    __shared__ float xsm[NPB][NODE_DIM];
    __shared__ float hsm[NPB][NODE_DIM];
    const int n0 = (blockIdx.x - PREP_BLOCKS) * NPB;
    const int half = t >> 7;
    const int tc = t & 127;

    #pragma unroll
    for (int i = 0; i < 2; ++i) {
        const int nn = 2 * half + i;
        const int node = n0 + nn;
        xsm[nn][tc] = (node < N_NODES) ? xs[(size_t)node * NODE_DIM + tc] : 0.f;
    }
    __syncthreads();

    float acc[2] = {b1[tc], b1[tc]};
    for (int k = 0; k < NODE_DIM; ++k) {
        const float w = W1[k * NODE_DIM + tc];
        #pragma unroll
        for (int i = 0; i < 2; ++i) acc[i] = fmaf(xsm[2 * half + i][k], w, acc[i]);
    }
    #pragma unroll
    for (int i = 0; i < 2; ++i) {
        const float v = acc[i];
        hsm[2 * half + i][tc] = v / (1.f + __expf(-v));
    }
    __syncthreads();

    for (int j = t; j < HIDDEN; j += 256) {
        float a2[NPB];
        #pragma unroll
        for (int n = 0; n < NPB; ++n) a2[n] = b2[j];
        for (int k = 0; k < NODE_DIM; ++k) {
            const float w = W2[k * HIDDEN + j];
            #pragma unroll
            for (int n = 0; n < NPB; ++n) a2[n] = fmaf(hsm[n][k], w, a2[n]);
        }
        #pragma unroll
        for (int n = 0; n < NPB; ++n) {
            const int node = n0 + n;
            if (node < N_NODES) so_bf[(size_t)node * HIDDEN + j] = f2bf(a2[n]);
        }
    }
}

// ---------------- padded CSR scan: poff = prefix of 16*ceil(deg/16); window maps ----------------
__global__ __launch_bounds__(1024) void scan_kernel(const int* __restrict__ counts,
                                                    int* __restrict__ poff,
                                                    int* __restrict__ cursor,
                                                    int* __restrict__ wnode,
                                                    int* __restrict__ wcnt,
                                                    int* __restrict__ nwin_d) {
    __shared__ int wsum[16];
    const int tid = threadIdx.x;
    int vals[10];
    int run = 0;
    #pragma unroll
    for (int i = 0; i < 10; ++i) {
        int idx = tid * 10 + i;
        int deg = (idx < N_NODES) ? counts[idx] : 0;
        int pc = ((deg + 15) >> 4) << 4;
        vals[i] = run;
        run += pc;
    }
    const int lane = tid & 63, w = tid >> 6;
    int inc = run;
    #pragma unroll
    for (int off = 1; off < 64; off <<= 1) {
        int v = __shfl_up(inc, off);
        if (lane >= off) inc += v;
    }
    if (lane == 63) wsum[w] = inc;
    __syncthreads();
    if (w == 0) {
        int v = (lane < 16) ? wsum[lane] : 0;
        #pragma unroll
        for (int off = 1; off < 16; off <<= 1) {
            int u = __shfl_up(v, off);
            if (lane >= off) v += u;
        }
        if (lane < 16) wsum[lane] = v;
    }
    __syncthreads();
    const int wbase = (w > 0) ? wsum[w - 1] : 0;
    const int base = wbase + inc - run;   // exclusive prefix (padded)
    #pragma unroll
    for (int i = 0; i < 10; ++i) {
        int idx = tid * 10 + i;
        if (idx < N_NODES) {
            const int p = base + vals[i];
            const int deg = counts[idx];
            poff[idx] = p;
            cursor[idx] = p;
            const int nw = (deg + 15) >> 4;
            const int wb = p >> 4;
            for (int k = 0; k < nw; ++k) {
                wnode[wb + k] = idx;
                wcnt[wb + k] = min(16, deg - 16 * k);
            }
        }
    }
    if (tid == 1023) nwin_d[0] = (wbase + inc) >> 4;
}

__global__ __launch_bounds__(256) void scatter_kernel(const int* __restrict__ eidx,
                                                      int* __restrict__ cursor,
                                                      int* __restrict__ edge_order) {
    int i = blockIdx.x * blockDim.x + threadIdx.x;
    if (i < N_EDGES) {
        int s = eidx[i];
        int pos = atomicAdd(&cursor[s], 1);
        edge_order[pos] = i;
    }
}

// ---------------- window MFMA kernel: 16 edges, ONE node per window ----------------
// Phase A: rbf(16x32 bf16) @ Wr-frags on matrix cores; fo -> paired bf16 LDS.
// Phase B: branch-free, atomic-free inner loop (loads batched in registers);
//          single atomic flush per window at the end.
__global__ __launch_bounds__(256, 4) void win_mfma(
    const float* __restrict__ xsp,
    const float* __restrict__ rbf, const float* __restrict__ fcut,
    const float* __restrict__ rsh, const int* __restrict__ eidx,
    const unsigned short* __restrict__ bfrag, const float* __restrict__ br,
    const unsigned short* __restrict__ so_bf,
    const int* __restrict__ edge_order,
    const int* __restrict__ wnode, const int* __restrict__ wcnt,
    const int* __restrict__ nwin_d,
    float* __restrict__ out_scalar, float* __restrict__ out_sph)
{
    __shared__ unsigned int   pair_s[EB][IRP];    // 14.9 KB
    __shared__ unsigned short scal_s[EB][SCP];    // 4.4 KB
    __shared__ int   e_s[EB];
    __shared__ int   dst_s[EB];
    __shared__ float fc_s[EB];

    const int win = blockIdx.x;
    if (win >= nwin_d[0]) return;
    const int t = threadIdx.x;
    const int n = wnode[win];
    const int cnt = wcnt[win];
    const int base = win * EB;
    const int lane = t & 63, w = t >> 6;

    // ---- stage meta (pads: fc=0 -> zero contribution) ----
    if (t < EB) {
        if (t < cnt) {
            const int e = edge_order[base + t];
            e_s[t]   = e;
            dst_s[t] = eidx[N_EDGES + e];
            fc_s[t]  = fcut[e];
        } else {
            e_s[t] = 0; dst_s[t] = 0; fc_s[t] = 0.f;
        }
    }
    __syncthreads();

    // ---- A-fragment from rbf rows (via e_s; lane: edge row l&15, k=(l>>4)*8+j) ----
    const int m_row = lane & 15;
    const int kb = (lane >> 4) * 8;
    short8v a0;
    {
        const float* rrow = rbf + (size_t)e_s[m_row] * NUM_BASIS;
        float q[8];
        if (kb < 16) {
            const float4 v0 = *(const float4*)(rrow + kb);
            const float4 v1 = *(const float4*)(rrow + kb + 4);
            q[0]=v0.x; q[1]=v0.y; q[2]=v0.z; q[3]=v0.w;
            q[4]=v1.x; q[5]=v1.y; q[6]=v1.z; q[7]=v1.w;
        } else if (kb == 16) {
            const float4 v0 = *(const float4*)(rrow + 16);
            q[0]=v0.x; q[1]=v0.y; q[2]=v0.z; q[3]=v0.w;
            q[4]=0.f; q[5]=0.f; q[6]=0.f; q[7]=0.f;
        } else {
            #pragma unroll
            for (int j = 0; j < 8; ++j) q[j] = 0.f;
        }
        #pragma unroll
        for (int j = 0; j < 8; ++j) a0[j] = (short)f2bf(q[j]);
    }

    // ---- phase A: 9 N-tiles per wave ----
    {
        const int rbase = (lane >> 4) * 4;
        int dA[4]; float fA[4];
        #pragma unroll
        for (int r = 0; r < 4; ++r) { dA[r] = dst_s[rbase + r]; fA[r] = fc_s[rbase + r]; }
        #pragma unroll
        for (int i = 0; i < NT / 4; ++i) {
            const int nt = w * (NT / 4) + i;
            const short8v bf = *(const short8v*)(bfrag + (size_t)(nt * 64 + lane) * 8);
            f32x4 c0 = {0.f, 0.f, 0.f, 0.f};
            c0 = __builtin_amdgcn_mfma_f32_16x16x32_bf16(a0, bf, c0, 0, 0, 0);
            const int col = nt * 16 + (lane & 15);
            const float brc = br[col];
            #pragma unroll
            for (int r = 0; r < 4; ++r) {
                const int row = rbase + r;
                const float sov = bf2f(so_bf[(size_t)dA[r] * HIDDEN + col]);
                const float v = (c0[r] + brc) * fA[r] * sov;
                const unsigned short hv = f2bf(v);
                if (col < NUM_IRREPS) {
                    ((unsigned short*)&pair_s[row][col])[0] = hv;              // state (lo)
                } else if (col < 2 * NUM_IRREPS) {
                    ((unsigned short*)&pair_s[row][col - NUM_IRREPS])[1] = hv; // edge (hi)
                } else {
                    scal_s[row][col - 2 * NUM_IRREPS] = hv;
                }
            }
        }
    }
    __syncthreads();

    // ---- phase B: branch-free; batched loads then FMA ----
    const bool sphOn = (t < 240);
    const int d0 = 2 * t;
    const int g0 = sphOn ? gate_of(d0) : 0;
    const int g1 = sphOn ? gate_of(d0 + 1) : 0;

    float accS = 0.f, accD0 = 0.f, accD1 = 0.f;

    if (sphOn) {
        float2 xv[EB], rv[EB];
        #pragma unroll
        for (int le = 0; le < EB; ++le) {
            xv[le] = *(const float2*)(xsp + (size_t)dst_s[le] * SPH_DIM + d0);
            rv[le] = *(const float2*)(rsh + (size_t)e_s[le]  * SPH_DIM + d0);
        }
        #pragma unroll
        for (int le = 0; le < EB; ++le) {
            const unsigned int p0 = pair_s[le][g0];
            const unsigned int p1 = pair_s[le][g1];
            accD0 = fmaf(xv[le].x, bf2f((unsigned short)(p0 & 0xffffu)),
                    fmaf(rv[le].x, bf2f((unsigned short)(p0 >> 16)), accD0));
            accD1 = fmaf(xv[le].y, bf2f((unsigned short)(p1 & 0xffffu)),
                    fmaf(rv[le].y, bf2f((unsigned short)(p1 >> 16)), accD1));
        }
    }
    if (t < 128) {
        #pragma unroll
        for (int le = 0; le < EB; ++le) accS += bf2f(scal_s[le][t]);
    }

    // ---- single flush per window ----
    if (sphOn) {
        atomicAdd(&out_sph[(size_t)n * SPH_DIM + d0],     accD0);
        atomicAdd(&out_sph[(size_t)n * SPH_DIM + d0 + 1], accD1);
    }
    if (t < 128) atomicAdd(&out_scalar[(size_t)n * NODE_DIM + t], accS);
}

extern "C" void kernel_launch(void* const* d_in, const int* in_sizes, int n_in,
                              void* d_out, int out_size, void* d_ws, size_t ws_size,
                              hipStream_t stream) {
    const float* x_scalar    = (const float*)d_in[0];
    const float* x_spherical = (const float*)d_in[1];
    const float* rbf         = (const float*)d_in[2];
    const float* fcut        = (const float*)d_in[3];
    const float* rsh         = (const float*)d_in[4];
    const int*   eidx        = (const int*)d_in[5];
    const float* W1          = (const float*)d_in[6];
    const float* b1          = (const float*)d_in[7];
    const float* W2          = (const float*)d_in[8];
    const float* b2          = (const float*)d_in[9];
    const float* Wr          = (const float*)d_in[10];
    const float* br          = (const float*)d_in[11];

    float* out        = (float*)d_out;
    float* out_scalar = out;                                   // (N_NODES, 128)
    float* out_sph    = out + (size_t)N_NODES * NODE_DIM;      // (N_NODES, 480)

    // workspace layout
    unsigned short* so_bf = (unsigned short*)d_ws;             // 10000*576 bf16
    int*   counts     = (int*)(so_bf + (size_t)N_NODES * HIDDEN);
    int*   poff       = counts + N_NODES;                      // 10000
    int*   cursor     = poff + N_NODES;                        // 10000
    int*   wnode      = cursor + N_NODES;                      // MAXW
    int*   wcnt       = wnode + MAXW;                          // MAXW
    int*   nwin_d     = wcnt + MAXW;                           // 1
    int*   edge_order = nwin_d + 1;                            // 16*MAXW
    unsigned short* bfrag = (unsigned short*)((((uintptr_t)(edge_order + (size_t)16 * MAXW)) + 15) & ~(uintptr_t)15);

    hipMemsetAsync(counts, 0, N_NODES * sizeof(int), stream);
    prep_mlp_kernel<<<PREP_BLOCKS + MLP_BLOCKS, 256, 0, stream>>>(
        x_scalar, x_spherical, out, eidx, counts, Wr, bfrag, W1, b1, W2, b2, so_bf);
    scan_kernel<<<1, 1024, 0, stream>>>(counts, poff, cursor, wnode, wcnt, nwin_d);
    scatter_kernel<<<(N_EDGES + 255) / 256, 256, 0, stream>>>(eidx, cursor, edge_order);
    win_mfma<<<MAXW, 256, 0, stream>>>(x_spherical, rbf, fcut, rsh, eidx,
                                       bfrag, br, so_bf, edge_order,
                                       wnode, wcnt, nwin_d,
                                       out_scalar, out_sph);
}

// Round 17
// 294.437 us; speedup vs baseline: 1.8424x; 1.1419x over previous
//
#include <hip/hip_runtime.h>

#define NODE_DIM 128
#define NUM_IRREPS 224
#define SPH_DIM 480
#define HIDDEN 576   // NODE_DIM + 2*NUM_IRREPS
#define NUM_BASIS 20
#define N_NODES 10000
#define N_EDGES 160000
#define NPB 4        // nodes per block in fused MLP
#define EB 16        // edges per window
#define NWIN (N_EDGES / EB)   // 10000 dense windows
#define NT 36        // N-tiles (576/16)
#define IRP 233      // pair row stride in words (odd)
#define SCP 138      // scal row stride in shorts
#define PROW 608     // partial row: 128 scal + 480 sph (bf16)
#define MAXP 20480   // >= nodes + window crossings (<= 19999)
#define PREP_BLOCKS 625
#define MLP_BLOCKS ((N_NODES + NPB - 1) / NPB)

typedef __attribute__((ext_vector_type(8))) short short8v;   // 8 bf16
typedef __attribute__((ext_vector_type(4))) float f32x4;

__device__ __forceinline__ unsigned short f2bf(float f) {
    unsigned int u = __builtin_bit_cast(unsigned int, f);
    u = (u + 0x7fff + ((u >> 16) & 1)) >> 16;   // RNE
    return (unsigned short)u;
}
__device__ __forceinline__ float bf2f(unsigned short h) {
    unsigned int u = ((unsigned int)h) << 16;
    return __builtin_bit_cast(float, u);
}
__device__ __forceinline__ int gate_of(int d) {
    return (d < 128) ? d : (d < 320) ? (128 + (d - 128) / 3) : (192 + (d - 320) / 5);
}

// ---------------- fused prep (histogram + bfrag) + node MLP ----------------
__global__ __launch_bounds__(256) void prep_mlp_kernel(
    const float* __restrict__ xs,
    const int* __restrict__ eidx, int* __restrict__ counts,
    const float* __restrict__ Wr, unsigned short* __restrict__ bfrag,
    const float* __restrict__ W1, const float* __restrict__ b1,
    const float* __restrict__ W2, const float* __restrict__ b2,
    unsigned short* __restrict__ so_bf)
{
    const int t = threadIdx.x;
    if (blockIdx.x < PREP_BLOCKS) {
        const int gt = blockIdx.x * 256 + t;
        if (gt < N_EDGES) atomicAdd(&counts[eidx[gt]], 1);
        if (blockIdx.x == PREP_BLOCKS - 1) {
            for (int idx = t; idx < NT * 64; idx += 256) {
                const int nt = idx >> 6, l = idx & 63;
                const int col = nt * 16 + (l & 15);
                const int kb = (l >> 4) * 8;
                #pragma unroll
                for (int j = 0; j < 8; ++j) {
                    const int k = kb + j;
                    bfrag[(size_t)idx * 8 + j] = (k < NUM_BASIS) ? f2bf(Wr[k * HIDDEN + col]) : (unsigned short)0;
                }
            }
        }
        return;
    }
    // ---- node MLP: 256 threads, 4 nodes/block ----
    __shared__ float xsm[NPB][NODE_DIM];
    __shared__ float hsm[NPB][NODE_DIM];
    const int n0 = (blockIdx.x - PREP_BLOCKS) * NPB;
    const int half = t >> 7;
    const int tc = t & 127;

    #pragma unroll
    for (int i = 0; i < 2; ++i) {
        const int nn = 2 * half + i;
        const int node = n0 + nn;
        xsm[nn][tc] = (node < N_NODES) ? xs[(size_t)node * NODE_DIM + tc] : 0.f;
    }
    __syncthreads();

    float acc[2] = {b1[tc], b1[tc]};
    for (int k = 0; k < NODE_DIM; ++k) {
        const float w = W1[k * NODE_DIM + tc];
        #pragma unroll
        for (int i = 0; i < 2; ++i) acc[i] = fmaf(xsm[2 * half + i][k], w, acc[i]);
    }
    #pragma unroll
    for (int i = 0; i < 2; ++i) {
        const float v = acc[i];
        hsm[2 * half + i][tc] = v / (1.f + __expf(-v));
    }
    __syncthreads();

    for (int j = t; j < HIDDEN; j += 256) {
        float a2[NPB];
        #pragma unroll
        for (int n = 0; n < NPB; ++n) a2[n] = b2[j];
        for (int k = 0; k < NODE_DIM; ++k) {
            const float w = W2[k * HIDDEN + j];
            #pragma unroll
            for (int n = 0; n < NPB; ++n) a2[n] = fmaf(hsm[n][k], w, a2[n]);
        }
        #pragma unroll
        for (int n = 0; n < NPB; ++n) {
            const int node = n0 + n;
            if (node < N_NODES) so_bf[(size_t)node * HIDDEN + j] = f2bf(a2[n]);
        }
    }
}

// ---------------- scan: off = prefix(deg); pairbase = prefix(windows-touched) ----------------
__global__ __launch_bounds__(1024) void scan_kernel(const int* __restrict__ counts,
                                                    int* __restrict__ offsets,
                                                    int* __restrict__ cursor,
                                                    int* __restrict__ pairbase) {
    __shared__ int wsum[16];
    const int tid = threadIdx.x;
    const int lane = tid & 63, w = tid >> 6;
    int deg[10], vals[10];

    // ---- pass 1: scan degrees -> offsets ----
    int run = 0;
    #pragma unroll
    for (int i = 0; i < 10; ++i) {
        int idx = tid * 10 + i;
        deg[i] = (idx < N_NODES) ? counts[idx] : 0;
        vals[i] = run;
        run += deg[i];
    }
    int inc = run;
    #pragma unroll
    for (int off = 1; off < 64; off <<= 1) {
        int v = __shfl_up(inc, off);
        if (lane >= off) inc += v;
    }
    if (lane == 63) wsum[w] = inc;
    __syncthreads();
    if (w == 0) {
        int v = (lane < 16) ? wsum[lane] : 0;
        #pragma unroll
        for (int off = 1; off < 16; off <<= 1) {
            int u = __shfl_up(v, off);
            if (lane >= off) v += u;
        }
        if (lane < 16) wsum[lane] = v;
    }
    __syncthreads();
    const int wbase = (w > 0) ? wsum[w - 1] : 0;
    const int base = wbase + inc - run;
    int off_n[10];
    #pragma unroll
    for (int i = 0; i < 10; ++i) {
        int idx = tid * 10 + i;
        off_n[i] = base + vals[i];
        if (idx < N_NODES) {
            offsets[idx] = off_n[i];
            cursor[idx] = off_n[i];
        }
    }
    if (tid == 1023) offsets[N_NODES] = wbase + inc;
    __syncthreads();

    // ---- pass 2: scan windows-touched -> pairbase ----
    int run2 = 0;
    int vals2[10];
    #pragma unroll
    for (int i = 0; i < 10; ++i) {
        int wins = (deg[i] > 0) ? (((off_n[i] + deg[i] - 1) >> 4) - (off_n[i] >> 4) + 1) : 0;
        vals2[i] = run2;
        run2 += wins;
    }
    int inc2 = run2;
    #pragma unroll
    for (int off = 1; off < 64; off <<= 1) {
        int v = __shfl_up(inc2, off);
        if (lane >= off) inc2 += v;
    }
    if (lane == 63) wsum[w] = inc2;
    __syncthreads();
    if (w == 0) {
        int v = (lane < 16) ? wsum[lane] : 0;
        #pragma unroll
        for (int off = 1; off < 16; off <<= 1) {
            int u = __shfl_up(v, off);
            if (lane >= off) v += u;
        }
        if (lane < 16) wsum[lane] = v;
    }
    __syncthreads();
    const int wbase2 = (w > 0) ? wsum[w - 1] : 0;
    const int base2 = wbase2 + inc2 - run2;
    #pragma unroll
    for (int i = 0; i < 10; ++i) {
        int idx = tid * 10 + i;
        if (idx < N_NODES) pairbase[idx] = base2 + vals2[i];
    }
    if (tid == 1023) pairbase[N_NODES] = wbase2 + inc2;
}

__global__ __launch_bounds__(256) void scatter_kernel(const int* __restrict__ eidx,
                                                      int* __restrict__ cursor,
                                                      int* __restrict__ edge_order,
                                                      int* __restrict__ edge_src) {
    int i = blockIdx.x * blockDim.x + threadIdx.x;
    if (i < N_EDGES) {
        int s = eidx[i];
        int pos = atomicAdd(&cursor[s], 1);
        edge_order[pos] = i;
        edge_src[pos] = s;
    }
}

// ---------------- edge MFMA kernel: 16 sorted edges/window, NO output atomics ----------------
// Phase A: identical to R13 (MFMA filter GEMM, fo -> paired bf16 LDS).
// Phase B: identical accumulate; per-segment flush = plain bf16 row store into
//   partials[pairbase[src] + (win - off[src]>>4)].
__global__ __launch_bounds__(256, 4) void edge_mfma(
    const float* __restrict__ xsp,
    const float* __restrict__ rbf, const float* __restrict__ fcut,
    const float* __restrict__ rsh, const int* __restrict__ eidx,
    const unsigned short* __restrict__ bfrag, const float* __restrict__ br,
    const unsigned short* __restrict__ so_bf,
    const int* __restrict__ edge_order, const int* __restrict__ edge_src,
    const int* __restrict__ offsets, const int* __restrict__ pairbase,
    unsigned short* __restrict__ partials)
{
    __shared__ unsigned int   pair_s[EB][IRP];    // 14.9 KB
    __shared__ unsigned short scal_s[EB][SCP];    // 4.4 KB
    __shared__ int   e_s[EB];
    __shared__ int   src_s[EB];
    __shared__ int   dst_s[EB];
    __shared__ int   off_s[EB];
    __shared__ int   pb_s[EB];
    __shared__ float fc_s[EB];

    const int t = threadIdx.x;
    const int win = blockIdx.x;
    const int base = win * EB;
    const int lane = t & 63, w = t >> 6;

    // ---- A-fragment: direct global load (lane l: edge row l&15, k=(l>>4)*8+j) ----
    const int m_row = lane & 15;
    const int kb = (lane >> 4) * 8;
    const int e_row = edge_order[base + m_row];
    short8v a0;
    {
        const float* rrow = rbf + (size_t)e_row * NUM_BASIS;
        #pragma unroll
        for (int j = 0; j < 8; ++j) {
            const int k = kb + j;
            a0[j] = (k < NUM_BASIS) ? (short)f2bf(rrow[k]) : (short)0;
        }
    }

    // ---- stage meta ----
    if (t < EB) {
        int pos = base + t;
        int e = edge_order[pos];
        int s = edge_src[pos];
        e_s[t]   = e;
        src_s[t] = s;
        dst_s[t] = eidx[N_EDGES + e];
        fc_s[t]  = fcut[e];
        off_s[t] = offsets[s];
        pb_s[t]  = pairbase[s];
    }
    __syncthreads();

    // ---- phase A: 9 N-tiles per wave ----
    {
        const int rbase = (lane >> 4) * 4;
        int   dA[4];
        float fA[4];
        #pragma unroll
        for (int r = 0; r < 4; ++r) { dA[r] = dst_s[rbase + r]; fA[r] = fc_s[rbase + r]; }
        #pragma unroll
        for (int i = 0; i < NT / 4; ++i) {
            const int nt = w * (NT / 4) + i;
            const short8v bf = *(const short8v*)(bfrag + (size_t)(nt * 64 + lane) * 8);
            f32x4 c0 = {0.f, 0.f, 0.f, 0.f};
            c0 = __builtin_amdgcn_mfma_f32_16x16x32_bf16(a0, bf, c0, 0, 0, 0);
            const int col = nt * 16 + (lane & 15);
            const float brc = br[col];
            #pragma unroll
            for (int r = 0; r < 4; ++r) {
                const int row = rbase + r;
                const float sov = bf2f(so_bf[(size_t)dA[r] * HIDDEN + col]);
                const float v = (c0[r] + brc) * fA[r] * sov;
                const unsigned short hv = f2bf(v);
                if (col < NUM_IRREPS) {
                    ((unsigned short*)&pair_s[row][col])[0] = hv;              // state (lo)
                } else if (col < 2 * NUM_IRREPS) {
                    ((unsigned short*)&pair_s[row][col - NUM_IRREPS])[1] = hv; // edge (hi)
                } else {
                    scal_s[row][col - 2 * NUM_IRREPS] = hv;
                }
            }
        }
    }
    __syncthreads();

    // ---- phase B: float2 consume, segmented accumulate, plain-store flush ----
    const bool sphOn = (t < 240);
    const int d0 = 2 * t;
    const int g0 = sphOn ? gate_of(d0) : 0;
    const int g1 = sphOn ? gate_of(d0 + 1) : 0;

    float accS = 0.f, accD0 = 0.f, accD1 = 0.f;
    int cur = 0;   // segment start (local index)

    #pragma unroll
    for (int le = 0; le < EB; ++le) {
        if (src_s[le] != src_s[cur]) {   // block-uniform branch
            const int prow = pb_s[cur] + (win - (off_s[cur] >> 4));
            unsigned short* pr = partials + (size_t)prow * PROW;
            if (t < 128) pr[t] = f2bf(accS);
            if (sphOn) {
                pr[NODE_DIM + d0]     = f2bf(accD0);
                pr[NODE_DIM + d0 + 1] = f2bf(accD1);
            }
            accD0 = accD1 = accS = 0.f;
            cur = le;
        }
        if (sphOn) {
            const float2 xv = *(const float2*)(xsp + (size_t)dst_s[le] * SPH_DIM + d0);
            const float2 rv = *(const float2*)(rsh + (size_t)e_s[le]  * SPH_DIM + d0);
            const unsigned int p0 = pair_s[le][g0];
            const unsigned int p1 = pair_s[le][g1];
            accD0 = fmaf(xv.x, bf2f((unsigned short)(p0 & 0xffffu)),
                    fmaf(rv.x, bf2f((unsigned short)(p0 >> 16)), accD0));
            accD1 = fmaf(xv.y, bf2f((unsigned short)(p1 & 0xffffu)),
                    fmaf(rv.y, bf2f((unsigned short)(p1 >> 16)), accD1));
        }
        if (t < 128) accS += bf2f(scal_s[le][t]);
    }
    {
        const int prow = pb_s[cur] + (win - (off_s[cur] >> 4));
        unsigned short* pr = partials + (size_t)prow * PROW;
        if (t < 128) pr[t] = f2bf(accS);
        if (sphOn) {
            pr[NODE_DIM + d0]     = f2bf(accD0);
            pr[NODE_DIM + d0 + 1] = f2bf(accD1);
        }
    }
}

// ---------------- finalize: out = x + sum(partial rows) ----------------
__global__ __launch_bounds__(256) void finalize_kernel(
    const float* __restrict__ xs, const float* __restrict__ xsp,
    const unsigned short* __restrict__ partials,
    const int* __restrict__ pairbase,
    float* __restrict__ out_scalar, float* __restrict__ out_sph)
{
    const int t = threadIdx.x;
    const int n = blockIdx.x;
    const int pb = pairbase[n], pe = pairbase[n + 1];
    const bool sphOn = (t < 240);
    const int d0 = 2 * t;

    float accS = 0.f, a0 = 0.f, a1 = 0.f;
    for (int p = pb; p < pe; ++p) {
        const unsigned short* pr = partials + (size_t)p * PROW;
        if (t < 128) accS += bf2f(pr[t]);
        if (sphOn) {
            a0 += bf2f(pr[NODE_DIM + d0]);
            a1 += bf2f(pr[NODE_DIM + d0 + 1]);
        }
    }
    if (t < 128)
        out_scalar[(size_t)n * NODE_DIM + t] = xs[(size_t)n * NODE_DIM + t] + accS;
    if (sphOn) {
        const float2 xv = *(const float2*)(xsp + (size_t)n * SPH_DIM + d0);
        float2 o; o.x = xv.x + a0; o.y = xv.y + a1;
        *(float2*)(out_sph + (size_t)n * SPH_DIM + d0) = o;
    }
}

extern "C" void kernel_launch(void* const* d_in, const int* in_sizes, int n_in,
                              void* d_out, int out_size, void* d_ws, size_t ws_size,
                              hipStream_t stream) {
    const float* x_scalar    = (const float*)d_in[0];
    const float* x_spherical = (const float*)d_in[1];
    const float* rbf         = (const float*)d_in[2];
    const float* fcut        = (const float*)d_in[3];
    const float* rsh         = (const float*)d_in[4];
    const int*   eidx        = (const int*)d_in[5];
    const float* W1          = (const float*)d_in[6];
    const float* b1          = (const float*)d_in[7];
    const float* W2          = (const float*)d_in[8];
    const float* b2          = (const float*)d_in[9];
    const float* Wr          = (const float*)d_in[10];
    const float* br          = (const float*)d_in[11];

    float* out        = (float*)d_out;
    float* out_scalar = out;                                   // (N_NODES, 128)
    float* out_sph    = out + (size_t)N_NODES * NODE_DIM;      // (N_NODES, 480)

    // workspace layout
    unsigned short* so_bf = (unsigned short*)d_ws;             // 10000*576 bf16
    unsigned short* partials = so_bf + (size_t)N_NODES * HIDDEN;          // MAXP*608 bf16
    int*   counts     = (int*)(partials + (size_t)MAXP * PROW);
    int*   offsets    = counts + N_NODES;                      // 10001
    int*   pairbase   = offsets + N_NODES + 1;                 // 10001
    int*   cursor     = pairbase + N_NODES + 1;                // 10000
    int*   edge_order = cursor + N_NODES;                      // 160000
    int*   edge_src   = edge_order + N_EDGES;                  // 160000
    unsigned short* bfrag = (unsigned short*)((((uintptr_t)(edge_src + N_EDGES)) + 15) & ~(uintptr_t)15);

    hipMemsetAsync(counts, 0, N_NODES * sizeof(int), stream);
    prep_mlp_kernel<<<PREP_BLOCKS + MLP_BLOCKS, 256, 0, stream>>>(
        x_scalar, eidx, counts, Wr, bfrag, W1, b1, W2, b2, so_bf);
    scan_kernel<<<1, 1024, 0, stream>>>(counts, offsets, cursor, pairbase);
    scatter_kernel<<<(N_EDGES + 255) / 256, 256, 0, stream>>>(eidx, cursor, edge_order, edge_src);
    edge_mfma<<<NWIN, 256, 0, stream>>>(x_spherical, rbf, fcut, rsh, eidx,
                                        bfrag, br, so_bf, edge_order, edge_src,
                                        offsets, pairbase, partials);
    finalize_kernel<<<N_NODES, 256, 0, stream>>>(x_scalar, x_spherical, partials, pairbase,
                                                 out_scalar, out_sph);
}